// Round 17
// baseline (460.091 us; speedup 1.0000x reference)
//
#include <hip/hip_runtime.h>

#define B_TOT 8192
#define T_OBS 128
#define T_FUT 64
#define T_ALL 192
#define DIN 5
#define HD 128
#define BT 16          // batch rows per block (one 16-row tile)
#define LDSTR 136      // LDS row stride in shorts (272 B, 16B-aligned rows)
#define NTHR 256       // 4 waves/block; 512 blocks -> 2 blocks/CU

#define LOG2E 1.44269504088896340736f

typedef __attribute__((ext_vector_type(8))) short short8;
typedef __attribute__((ext_vector_type(4))) float f32x4;
typedef __attribute__((ext_vector_type(2))) unsigned int u32x2;
typedef __attribute__((ext_vector_type(4))) unsigned int u32x4;

__device__ inline short f2bf(float f) {
    unsigned u = __float_as_uint(f);
    u += 0x7FFFu + ((u >> 16) & 1u);   // round-to-nearest-even
    return (short)(u >> 16);
}

// packed f32->bf16 (RNE), lo <- s0, hi <- s1
__device__ inline unsigned cvtpk(float lo, float hi) {
    unsigned r;
    asm volatile("v_cvt_pk_bf16_f32 %0, %1, %2" : "=v"(r) : "v"(lo), "v"(hi));
    return r;
}

__device__ inline f32x4 MFMA(short8 a, short8 b, f32x4 c) {
    return __builtin_amdgcn_mfma_f32_16x16x32_bf16(a, b, c, 0, 0, 0);
}

__device__ inline short8 load_w8s(const float* p, float s) {
    float4 a = *reinterpret_cast<const float4*>(p);
    float4 b = *reinterpret_cast<const float4*>(p + 4);
    short8 r;
    r[0] = f2bf(a.x * s); r[1] = f2bf(a.y * s); r[2] = f2bf(a.z * s); r[3] = f2bf(a.w * s);
    r[4] = f2bf(b.x * s); r[5] = f2bf(b.y * s); r[6] = f2bf(b.z * s); r[7] = f2bf(b.w * s);
    return r;
}
__device__ inline short8 load_w5s(const float* p, float s) {
    short8 r = (short8)0;
    r[0] = f2bf(p[0] * s); r[1] = f2bf(p[1] * s); r[2] = f2bf(p[2] * s);
    r[3] = f2bf(p[3] * s); r[4] = f2bf(p[4] * s);
    return r;
}

// R15 (2nd resubmit; never executed due to broker timeouts): 256 threads =
// 4 waves, BT=16 -> 512 blocks -> target 2 blocks/CU with independent
// per-block barriers.
//
// CO-RESIDENCY MODEL (R13+R14 separation): 2 waves/SIMD requires TOTAL
// (arch VGPR + hidden AGPR accumulators) <= 256/wave.
//   R13: total <=256 (spilling) -> co-resident (occ 20.5%), 323 us.
//   R14: no spill but 188 arch + ~70 AGPR ~= 260 > 256 -> occ 11.7%,
//        395 us (and halving waves cost only +44% vs R12 -> waves idle).
// R15 fix: biases move to per-wave LDS slots (R5-R10 validated mechanism)
// -> ~156 arch + ~70 AGPR ~= 226 <= 256. launch_bounds(256,1) keeps the
// allocator unconstrained (no artificial cap).
//
// Wave w owns gate-cols [32w,32w+32) of r/z/n as two 16-col slices
// (30 MFMA/wave/step); block's 16 rows are one B-tile shared by both
// slices -> 4 b128 LDS reads/lane/step. Head weights+bias in LDS.
// Loop split (R12, validated) retained.
__global__ __launch_bounds__(NTHR, 1)
void gru_tracemodel_kernel(const float* __restrict__ obs, const float* __restrict__ target,
                           const float* __restrict__ eWih, const float* __restrict__ eWhh,
                           const float* __restrict__ ebih, const float* __restrict__ ebhh,
                           const float* __restrict__ cWih, const float* __restrict__ cWhh,
                           const float* __restrict__ cbih, const float* __restrict__ cbhh,
                           const float* __restrict__ headW, const float* __restrict__ headb,
                           float* __restrict__ out)
{
    __shared__ __attribute__((aligned(16))) short Abuf[2][BT][LDSTR];
    __shared__ __attribute__((aligned(16))) short Hw[DIN][LDSTR];        // head W, bf16
    __shared__ __attribute__((aligned(16))) float Bias2[4][2][4][4][4];  // [wave][g][arr][q][r]
    __shared__ float HbLds[8];

    const int tid  = threadIdx.x;
    const int wave = tid >> 6;     // 0..3
    const int lane = tid & 63;
    const int q    = lane >> 4;    // k-group of A/B frags; row-group of C/D
    const int c    = lane & 15;    // non-K index of A/B frags; col of C/D
    const int b0   = blockIdx.x * BT;
    const int wb0  = wave * 32;    // this wave's 32 gate-cols (2 slices)

    // h0 = 0
    for (int i = tid; i < 2 * BT * LDSTR; i += NTHR) ((short*)Abuf)[i] = 0;

    // ---- weight fragments (A-operand: lane holds W'[n][k]) ----
    // [g] = 16-col slice; kt 0..3: Whh K-tiles; kt 4: zero-padded Wih x-tile
    short8 Wr[2][5], Wz[2][5], Wn[2][5];

    auto load_phase = [&](const float* Wih, const float* Whh) {
        #pragma unroll
        for (int g = 0; g < 2; ++g) {
            const int nr = 0 * HD + wb0 + 16 * g + c;
            const int nz = 1 * HD + wb0 + 16 * g + c;
            const int nn = 2 * HD + wb0 + 16 * g + c;
            #pragma unroll
            for (int kt = 0; kt < 4; ++kt) {
                Wr[g][kt] = load_w8s(Whh + nr * HD + kt * 32 + q * 8, LOG2E);
                Wz[g][kt] = load_w8s(Whh + nz * HD + kt * 32 + q * 8, LOG2E);
                Wn[g][kt] = load_w8s(Whh + nn * HD + kt * 32 + q * 8, 2.f * LOG2E);
            }
            Wr[g][4] = (q == 0) ? load_w5s(Wih + nr * DIN, LOG2E) : (short8)0;
            Wz[g][4] = (q == 0) ? load_w5s(Wih + nz * DIN, LOG2E) : (short8)0;
            Wn[g][4] = (q == 0) ? load_w5s(Wih + nn * DIN, 2.f * LOG2E) : (short8)0;
        }
    };
    // biases -> this wave's LDS slot (f32 exact; pre-scaled by log2e /
    // 2log2e). Lanes c==0 and c==1 write slices g=0,1 per q-group. Each
    // wave writes and reads only its own slot; compiler lgkmcnt orders
    // the within-wave write->read (no barrier needed).
    auto load_bias = [&](const float* bih, const float* bhh) {
        if (c < 2) {
            const int g  = c;
            const int n0 = wb0 + 16 * g + q * 4;
            f32x4 v0, v1, v2, v3;
            #pragma unroll
            for (int r = 0; r < 4; ++r) {
                v0[r] = (bih[0 * HD + n0 + r] + bhh[0 * HD + n0 + r]) * LOG2E;
                v1[r] = (bih[1 * HD + n0 + r] + bhh[1 * HD + n0 + r]) * LOG2E;
                v2[r] = bih[2 * HD + n0 + r] * (2.f * LOG2E);
                v3[r] = bhh[2 * HD + n0 + r] * (2.f * LOG2E);
            }
            *reinterpret_cast<f32x4*>(&Bias2[wave][g][0][q][0]) = v0;
            *reinterpret_cast<f32x4*>(&Bias2[wave][g][1][q][0]) = v1;
            *reinterpret_cast<f32x4*>(&Bias2[wave][g][2][q][0]) = v2;
            *reinterpret_cast<f32x4*>(&Bias2[wave][g][3][q][0]) = v3;
        }
    };
    load_phase(eWih, eWhh);
    load_bias(ebih, ebhh);

    // head weights -> LDS once (wave 0); first read far behind barriers
    if (wave == 0 && c < DIN) {
        #pragma unroll
        for (int kt = 0; kt < 4; ++kt) {
            short8 w = load_w8s(headW + c * HD + kt * 32 + q * 8, 1.f);
            *reinterpret_cast<short8*>(&Hw[c][kt * 32 + q * 8]) = w;
        }
    }
    if (tid < 8) HbLds[tid] = (tid < DIN) ? headb[tid] : 0.f;

    // fp32 carried h: hreg[g][r] = h[batch c][gate-dim wb0+16g+q*4+r]
    float hreg[2][4] = {{0.f,0.f,0.f,0.f},{0.f,0.f,0.f,0.f}};

    const float* obsr = obs    + (size_t)(b0 + c) * (T_OBS * DIN);
    const float* tgtr = target + (size_t)(b0 + c) * (T_FUT * DIN);
    float x5[5] = {0, 0, 0, 0, 0};
    if (q == 0) {
        float4 v4 = *reinterpret_cast<const float4*>(obsr);
        x5[0] = v4.x; x5[1] = v4.y; x5[2] = v4.z; x5[3] = v4.w;
        x5[4] = obsr[4];
    }

// One GRU time step. T runtime; DO_HEAD/ENC are 0/1 literals (dead-folded).
#define GRU_STEP(T, DO_HEAD, ENC)                                              \
  {                                                                            \
    __syncthreads();                                                           \
    const int p_ = (T) & 1;                                                    \
    short8 ah[4];                                                              \
    {                                                                          \
      const short* ap = &Abuf[p_][c][0];                                       \
      _Pragma("unroll")                                                        \
      for (int kt = 0; kt < 4; ++kt)                                           \
        ah[kt] = *reinterpret_cast<const short8*>(ap + kt * 32 + q * 8);       \
    }                                                                          \
    if (DO_HEAD) {                                                             \
      const int s_ = (T) - (T_OBS + 1);                                        \
      if (wave == (s_ & 3)) {                                                  \
        const short* hwp = &Hw[(c < DIN) ? c : 0][0];                          \
        f32x4 acc = {0.f, 0.f, 0.f, 0.f};                                      \
        _Pragma("unroll")                                                      \
        for (int kt = 0; kt < 4; ++kt) {                                       \
          short8 wh = *reinterpret_cast<const short8*>(hwp + kt * 32 + q * 8); \
          acc = MFMA(wh, ah[kt], acc);                                         \
        }                                                                      \
        const int d0 = q * 4;                                                  \
        if (d0 < DIN) {                                                        \
          float* op = out + ((size_t)(b0 + c) * T_FUT + s_) * DIN + d0;        \
          op[0] = acc[0] + HbLds[d0];                                          \
          if (q == 0) {                                                        \
            op[1] = acc[1] + HbLds[1];                                         \
            op[2] = acc[2] + HbLds[2];                                         \
            op[3] = acc[3] + HbLds[3];                                         \
          }                                                                    \
        }                                                                      \
      }                                                                        \
    }                                                                          \
    short8 ax;                                                                 \
    {                                                                          \
      u32x4 va = { cvtpk(x5[0], x5[1]), cvtpk(x5[2], x5[3]),                   \
                   cvtpk(x5[4], 0.f), 0u };                                    \
      ax = __builtin_bit_cast(short8, va);                                     \
      if (q == 0) {                                                            \
        const int tn_ = (T) + 1;                                               \
        const float* px = (ENC)                                                \
            ? (obsr + ((tn_ < T_OBS) ? tn_ : (T_OBS - 1)) * DIN)               \
            : (tgtr + (tn_ - T_OBS - 1) * DIN);                                \
        float4 v4 = *reinterpret_cast<const float4*>(px);                      \
        x5[0] = v4.x; x5[1] = v4.y; x5[2] = v4.z; x5[3] = v4.w;                \
        x5[4] = px[4];                                                         \
      }                                                                        \
    }                                                                          \
    _Pragma("unroll")                                                          \
    for (int g = 0; g < 2; ++g) {                                              \
      const f32x4 bR  = *reinterpret_cast<const f32x4*>(&Bias2[wave][g][0][q][0]); \
      const f32x4 bZ  = *reinterpret_cast<const f32x4*>(&Bias2[wave][g][1][q][0]); \
      const f32x4 bNi = *reinterpret_cast<const f32x4*>(&Bias2[wave][g][2][q][0]); \
      const f32x4 bNh = *reinterpret_cast<const f32x4*>(&Bias2[wave][g][3][q][0]); \
      f32x4 aR  = MFMA(Wr[g][0], ah[0], bR);                                   \
      f32x4 aZ  = MFMA(Wz[g][0], ah[0], bZ);                                   \
      f32x4 aNh = MFMA(Wn[g][0], ah[0], bNh);                                  \
      _Pragma("unroll")                                                        \
      for (int kt = 1; kt < 4; ++kt) {                                         \
        aR  = MFMA(Wr[g][kt], ah[kt], aR);                                     \
        aZ  = MFMA(Wz[g][kt], ah[kt], aZ);                                     \
        aNh = MFMA(Wn[g][kt], ah[kt], aNh);                                    \
      }                                                                        \
      aR  = MFMA(Wr[g][4], ax, aR);                                            \
      aZ  = MFMA(Wz[g][4], ax, aZ);                                            \
      f32x4 aNi = MFMA(Wn[g][4], ax, bNi);                                     \
      float hn[4];                                                             \
      _Pragma("unroll")                                                        \
      for (int r = 0; r < 4; ++r) {                                            \
        float er  = __builtin_amdgcn_exp2f(-aR[r]);                            \
        float rv  = __builtin_amdgcn_rcpf(1.f + er);                           \
        float yv  = fmaf(rv, aNh[r], aNi[r]);                                  \
        float ey  = __builtin_amdgcn_exp2f(yv);                                \
        float ez  = __builtin_amdgcn_exp2f(-aZ[r]);                            \
        float d2  = 1.f + ey;                                                  \
        float d1  = 1.f + ez;                                                  \
        float em1 = ey - 1.f;                                                  \
        float num = fmaf(ez, em1, hreg[g][r] * d2);                            \
        float h_  = num * __builtin_amdgcn_rcpf(d1 * d2);                      \
        hreg[g][r] = h_;                                                       \
        hn[r] = h_;                                                            \
      }                                                                        \
      u32x2 wv = { cvtpk(hn[0], hn[1]), cvtpk(hn[2], hn[3]) };                 \
      *reinterpret_cast<u32x2*>(                                               \
          &Abuf[1 - p_][c][wb0 + 16 * g + q * 4]) = wv;                        \
    }                                                                          \
  }

    // encoder: t = 0..127 (no head; x from obs, clamped select for t=127)
    for (int t = 0; t < T_OBS; ++t) GRU_STEP(t, 0, 1);

    // transition: switch to cell weights (registers + own-wave LDS bias
    // slot; between barriers, no cross-wave hazard)
    load_phase(cWih, cWhh);
    load_bias(cbih, cbhh);
    GRU_STEP(T_OBS, 0, 0);   // t = 128; prefetch target[0]

    // rollout: t = 129..191 (head fires for s = t-129; guard-free prefetch)
    for (int t = T_OBS + 1; t < T_ALL; ++t) GRU_STEP(t, 1, 0);

    // final: t = 192 -- head only, fired by wave 3 (s = 63)
    __syncthreads();
    if (wave == ((T_FUT - 1) & 3)) {
        const int p_ = T_ALL & 1;
        const int s_ = T_FUT - 1;
        const int d0 = q * 4;
        const short* ap  = &Abuf[p_][c][0];
        const short* hwp = &Hw[(c < DIN) ? c : 0][0];
        f32x4 acc = {0.f, 0.f, 0.f, 0.f};
        #pragma unroll
        for (int kt = 0; kt < 4; ++kt) {
            short8 h8 = *reinterpret_cast<const short8*>(ap + kt * 32 + q * 8);
            short8 wh = *reinterpret_cast<const short8*>(hwp + kt * 32 + q * 8);
            acc = MFMA(wh, h8, acc);
        }
        if (d0 < DIN) {
            float* op = out + ((size_t)(b0 + c) * T_FUT + s_) * DIN + d0;
            op[0] = acc[0] + HbLds[d0];
            if (q == 0) {
                op[1] = acc[1] + HbLds[1];
                op[2] = acc[2] + HbLds[2];
                op[3] = acc[3] + HbLds[3];
            }
        }
    }
#undef GRU_STEP
}

extern "C" void kernel_launch(void* const* d_in, const int* in_sizes, int n_in,
                              void* d_out, int out_size, void* d_ws, size_t ws_size,
                              hipStream_t stream)
{
    (void)in_sizes; (void)n_in; (void)d_ws; (void)ws_size; (void)out_size;
    gru_tracemodel_kernel<<<dim3(B_TOT / BT), dim3(NTHR), 0, stream>>>(
        (const float*)d_in[0],  (const float*)d_in[1],
        (const float*)d_in[2],  (const float*)d_in[3],
        (const float*)d_in[4],  (const float*)d_in[5],
        (const float*)d_in[6],  (const float*)d_in[7],
        (const float*)d_in[8],  (const float*)d_in[9],
        (const float*)d_in[10], (const float*)d_in[11],
        (float*)d_out);
}

// Round 19
// 321.220 us; speedup vs baseline: 1.4323x; 1.4323x over previous
//
#include <hip/hip_runtime.h>

#define B_TOT 8192
#define T_OBS 128
#define T_FUT 64
#define T_ALL 192
#define DIN 5
#define HD 128
#define BT 32          // batch rows per block (two 16-row tiles)
#define LDSTR 136      // LDS row stride in shorts (272 B, 16B-aligned rows)

#define LOG2E 1.44269504088896340736f

typedef __attribute__((ext_vector_type(8))) short short8;
typedef __attribute__((ext_vector_type(4))) float f32x4;
typedef __attribute__((ext_vector_type(2))) unsigned int u32x2;
typedef __attribute__((ext_vector_type(4))) unsigned int u32x4;

__device__ inline short f2bf(float f) {
    unsigned u = __float_as_uint(f);
    u += 0x7FFFu + ((u >> 16) & 1u);   // round-to-nearest-even
    return (short)(u >> 16);
}

// packed f32->bf16 (RNE), lo <- s0, hi <- s1
__device__ inline unsigned cvtpk(float lo, float hi) {
    unsigned r;
    asm volatile("v_cvt_pk_bf16_f32 %0, %1, %2" : "=v"(r) : "v"(lo), "v"(hi));
    return r;
}

__device__ inline f32x4 MFMA(short8 a, short8 b, f32x4 c) {
    return __builtin_amdgcn_mfma_f32_16x16x32_bf16(a, b, c, 0, 0, 0);
}

__device__ inline short8 load_w8s(const float* p, float s) {
    float4 a = *reinterpret_cast<const float4*>(p);
    float4 b = *reinterpret_cast<const float4*>(p + 4);
    short8 r;
    r[0] = f2bf(a.x * s); r[1] = f2bf(a.y * s); r[2] = f2bf(a.z * s); r[3] = f2bf(a.w * s);
    r[4] = f2bf(b.x * s); r[5] = f2bf(b.y * s); r[6] = f2bf(b.z * s); r[7] = f2bf(b.w * s);
    return r;
}
__device__ inline short8 load_w5s(const float* p, float s) {
    short8 r = (short8)0;
    r[0] = f2bf(p[0] * s); r[1] = f2bf(p[1] * s); r[2] = f2bf(p[2] * s);
    r[3] = f2bf(p[3] * s); r[4] = f2bf(p[4] * s);
    return r;
}

// FINAL (R12, verified 274.6 us in Round 12; baseline was 401.9 us).
// 512 threads = 8 waves, 256 blocks = 1 block/CU. Wave w owns gate-cols
// [16w,16w+16) of r/z/n (15 short8 weight frags = 60 VGPR); block owns 32
// rows as two 16-row B-tiles. Swapped MFMA (A=weights, B=h^T): lane's C/D
// holds 4 consecutive gate-dims of one batch row -> writeback is 2 cvt_pk
// + 1 b64 store. Weights pre-scaled by log2e (2log2e for n) so all
// transcendentals are bare v_exp_f32; combined-denominator elementwise =
// 3 exp2 + 2 rcp per element. Loop split removes per-step mode tests.
//
// CLOSED PATHS (hard evidence, do not revisit):
//  - >8 waves/CU: 64-VGPR wall + ~600 MB scratch spill (R1/R4/R5/R6/R7;
//    launch_bounds arg2 / waves_per_eu / flat_work_group_size all tried).
//  - 2 blocks/CU co-residency: observed ONLY at VGPR_Count <= 128
//    (R1@64 ok, R13@128 ok; R2/R10/R14/R15 at 100-188 all pinned to
//    1 block/CU). Weight-resident design needs >=150 -> closed.
//  - LDS XOR swizzle of Abuf: reads already conflict-free at the 8-lane
//    port grouping; swizzle quadrupled conflicts (R11, 4.4x). Residual
//    1.58e7 conflicts cost only ~8 us (R9/R11 A/B calibration).
//  - Weight streaming from L2: ~145 us floor (19.6 MB/CU / 34.5 TB/s)
//    before compute; not attempted (unfavorable risk/reward).
//
// Structural ceiling: 192-step serial recurrence, latency-bound with
// 2 lockstep waves/SIMD; per-step pipe floors (trans ~640 cyc/SIMD,
// MFMA ~300, LDS ~830/CU) are all well under the measured ~3430 cyc.
__global__ __launch_bounds__(512, 1)
void gru_tracemodel_kernel(const float* __restrict__ obs, const float* __restrict__ target,
                           const float* __restrict__ eWih, const float* __restrict__ eWhh,
                           const float* __restrict__ ebih, const float* __restrict__ ebhh,
                           const float* __restrict__ cWih, const float* __restrict__ cWhh,
                           const float* __restrict__ cbih, const float* __restrict__ cbhh,
                           const float* __restrict__ headW, const float* __restrict__ headb,
                           float* __restrict__ out)
{
    __shared__ __attribute__((aligned(16))) short Abuf[2][BT][LDSTR];

    const int tid   = threadIdx.x;
    const int wave  = tid >> 6;    // 0..7
    const int lane  = tid & 63;
    const int q     = lane >> 4;   // k-group of A/B frags; row-group of C/D
    const int c     = lane & 15;   // non-K index of A/B frags; col of C/D
    const int b0    = blockIdx.x * BT;
    const int wbase = wave * 16;   // this wave's gate-column slice

    // h0 = 0
    for (int i = tid; i < 2 * BT * LDSTR; i += 512) ((short*)Abuf)[i] = 0;

    // ---- weight fragments (A-operand: lane holds W'[n = wbase+c][k]) ----
    // kt 0..3: Whh K-tiles; kt 4: zero-padded Wih x-tile (only q==0 nonzero)
    short8 Wr[5], Wz[5], Wn[5];
    f32x4  br4, bz4, bnh4, bni4;   // per-reg biases: n = wbase + q*4 + r

    auto load_phase = [&](const float* Wih, const float* Whh,
                          const float* bih, const float* bhh) {
        const int nr = 0 * HD + wbase + c;
        const int nz = 1 * HD + wbase + c;
        const int nn = 2 * HD + wbase + c;
        #pragma unroll
        for (int kt = 0; kt < 4; ++kt) {
            Wr[kt] = load_w8s(Whh + nr * HD + kt * 32 + q * 8, LOG2E);
            Wz[kt] = load_w8s(Whh + nz * HD + kt * 32 + q * 8, LOG2E);
            Wn[kt] = load_w8s(Whh + nn * HD + kt * 32 + q * 8, 2.f * LOG2E);
        }
        Wr[4] = (q == 0) ? load_w5s(Wih + nr * DIN, LOG2E) : (short8)0;
        Wz[4] = (q == 0) ? load_w5s(Wih + nz * DIN, LOG2E) : (short8)0;
        Wn[4] = (q == 0) ? load_w5s(Wih + nn * DIN, 2.f * LOG2E) : (short8)0;
        const int n0 = wbase + q * 4;
        #pragma unroll
        for (int r = 0; r < 4; ++r) {
            br4[r]  = (bih[0 * HD + n0 + r] + bhh[0 * HD + n0 + r]) * LOG2E;
            bz4[r]  = (bih[1 * HD + n0 + r] + bhh[1 * HD + n0 + r]) * LOG2E;
            bni4[r] = bih[2 * HD + n0 + r] * (2.f * LOG2E);
            bnh4[r] = bhh[2 * HD + n0 + r] * (2.f * LOG2E);
        }
    };
    load_phase(eWih, eWhh, ebih, ebhh);

    // head fragments (all waves hold them; firing wave rotates per step).
    short8 Whd[4];
    f32x4  hb4;
    #pragma unroll
    for (int kt = 0; kt < 4; ++kt)
        Whd[kt] = (c < DIN) ? load_w8s(headW + c * HD + kt * 32 + q * 8, 1.f) : (short8)0;
    #pragma unroll
    for (int r = 0; r < 4; ++r)
        hb4[r] = (q * 4 + r < DIN) ? headb[q * 4 + r] : 0.f;

    // fp32 carried h: hreg[a][r] = h[batch a*16+c][gate-dim wbase+q*4+r]
    float hreg[2][4] = {{0.f,0.f,0.f,0.f},{0.f,0.f,0.f,0.f}};

    const float* obsr[2] = { obs + (size_t)(b0 + c) * (T_OBS * DIN),
                             obs + (size_t)(b0 + 16 + c) * (T_OBS * DIN) };
    const float* tgtr[2] = { target + (size_t)(b0 + c) * (T_FUT * DIN),
                             target + (size_t)(b0 + 16 + c) * (T_FUT * DIN) };
    float x5[2][5] = {{0,0,0,0,0},{0,0,0,0,0}};
    if (q == 0) {
        #pragma unroll
        for (int a = 0; a < 2; ++a) {
            float4 v4 = *reinterpret_cast<const float4*>(obsr[a]);
            x5[a][0] = v4.x; x5[a][1] = v4.y; x5[a][2] = v4.z; x5[a][3] = v4.w;
            x5[a][4] = obsr[a][4];
        }
    }

// One GRU time step. T is runtime, DO_HEAD/ENC are 0/1 literals so dead
// branches fold at compile time in each loop region.
#define GRU_STEP(T, DO_HEAD, ENC)                                              \
  {                                                                            \
    __syncthreads();                                                           \
    const int p_ = (T) & 1;                                                    \
    short8 ah[2][4];                                                           \
    _Pragma("unroll")                                                          \
    for (int a = 0; a < 2; ++a) {                                              \
      const short* ap = &Abuf[p_][a * 16 + c][0];                              \
      _Pragma("unroll")                                                        \
      for (int kt = 0; kt < 4; ++kt)                                           \
        ah[a][kt] = *reinterpret_cast<const short8*>(ap + kt * 32 + q * 8);    \
    }                                                                          \
    if (DO_HEAD) {                                                             \
      const int s_ = (T) - (T_OBS + 1);                                        \
      if (wave == (s_ & 7)) {                                                  \
        const int d0 = q * 4;                                                  \
        _Pragma("unroll")                                                      \
        for (int a = 0; a < 2; ++a) {                                          \
          f32x4 acc = hb4;                                                     \
          _Pragma("unroll")                                                    \
          for (int kt = 0; kt < 4; ++kt)                                       \
            acc = MFMA(Whd[kt], ah[a][kt], acc);                               \
          if (d0 < DIN) {                                                      \
            float* op = out + ((size_t)(b0 + a * 16 + c) * T_FUT + s_) * DIN + d0; \
            op[0] = acc[0];                                                    \
            if (q == 0) { op[1] = acc[1]; op[2] = acc[2]; op[3] = acc[3]; }    \
          }                                                                    \
        }                                                                      \
      }                                                                        \
    }                                                                          \
    short8 ax[2];                                                              \
    {                                                                          \
      u32x4 va = { cvtpk(x5[0][0], x5[0][1]), cvtpk(x5[0][2], x5[0][3]),       \
                   cvtpk(x5[0][4], 0.f), 0u };                                 \
      u32x4 vb = { cvtpk(x5[1][0], x5[1][1]), cvtpk(x5[1][2], x5[1][3]),       \
                   cvtpk(x5[1][4], 0.f), 0u };                                 \
      ax[0] = __builtin_bit_cast(short8, va);                                  \
      ax[1] = __builtin_bit_cast(short8, vb);                                  \
      if (q == 0) {                                                            \
        const int tn_ = (T) + 1;                                               \
        _Pragma("unroll")                                                      \
        for (int a = 0; a < 2; ++a) {                                          \
          const float* px = (ENC)                                              \
              ? (obsr[a] + ((tn_ < T_OBS) ? tn_ : (T_OBS - 1)) * DIN)          \
              : (tgtr[a] + (tn_ - T_OBS - 1) * DIN);                           \
          float4 v4 = *reinterpret_cast<const float4*>(px);                    \
          x5[a][0] = v4.x; x5[a][1] = v4.y; x5[a][2] = v4.z; x5[a][3] = v4.w;  \
          x5[a][4] = px[4];                                                    \
        }                                                                      \
      }                                                                        \
    }                                                                          \
    _Pragma("unroll")                                                          \
    for (int a = 0; a < 2; ++a) {                                              \
      f32x4 aR  = MFMA(Wr[0], ah[a][0], br4);                                  \
      f32x4 aZ  = MFMA(Wz[0], ah[a][0], bz4);                                  \
      f32x4 aNh = MFMA(Wn[0], ah[a][0], bnh4);                                 \
      _Pragma("unroll")                                                        \
      for (int kt = 1; kt < 4; ++kt) {                                         \
        aR  = MFMA(Wr[kt], ah[a][kt], aR);                                     \
        aZ  = MFMA(Wz[kt], ah[a][kt], aZ);                                     \
        aNh = MFMA(Wn[kt], ah[a][kt], aNh);                                    \
      }                                                                        \
      aR  = MFMA(Wr[4], ax[a], aR);                                            \
      aZ  = MFMA(Wz[4], ax[a], aZ);                                            \
      f32x4 aNi = MFMA(Wn[4], ax[a], bni4);                                    \
      float hn[4];                                                             \
      _Pragma("unroll")                                                        \
      for (int r = 0; r < 4; ++r) {                                            \
        float er  = __builtin_amdgcn_exp2f(-aR[r]);                            \
        float rv  = __builtin_amdgcn_rcpf(1.f + er);                           \
        float yv  = fmaf(rv, aNh[r], aNi[r]);                                  \
        float ey  = __builtin_amdgcn_exp2f(yv);                                \
        float ez  = __builtin_amdgcn_exp2f(-aZ[r]);                            \
        float d2  = 1.f + ey;                                                  \
        float d1  = 1.f + ez;                                                  \
        float em1 = ey - 1.f;                                                  \
        float num = fmaf(ez, em1, hreg[a][r] * d2);                            \
        float h_  = num * __builtin_amdgcn_rcpf(d1 * d2);                      \
        hreg[a][r] = h_;                                                       \
        hn[r] = h_;                                                            \
      }                                                                        \
      u32x2 wv = { cvtpk(hn[0], hn[1]), cvtpk(hn[2], hn[3]) };                 \
      *reinterpret_cast<u32x2*>(&Abuf[1 - p_][a * 16 + c][wbase + q * 4]) = wv;\
    }                                                                          \
  }

    // encoder: t = 0..127 (no head; x from obs, clamped select for t=127)
    for (int t = 0; t < T_OBS; ++t) GRU_STEP(t, 0, 1);

    // transition: switch to cell weights (register-only; between barriers)
    load_phase(cWih, cWhh, cbih, cbhh);
    GRU_STEP(T_OBS, 0, 0);   // t = 128; prefetch target[0]

    // rollout: t = 129..191 (head fires for s = t-129; prefetch guard-free:
    // idx t-128 <= 63 is always a valid target row)
    for (int t = T_OBS + 1; t < T_ALL; ++t) GRU_STEP(t, 1, 0);

    // final: t = 192 -- head only, fired by wave 7 (s=63); other waves done
    __syncthreads();
    if (wave == ((T_FUT - 1) & 7)) {
        const int p_ = T_ALL & 1;
        const int s_ = T_FUT - 1;
        const int d0 = q * 4;
        #pragma unroll
        for (int a = 0; a < 2; ++a) {
            const short* ap = &Abuf[p_][a * 16 + c][0];
            f32x4 acc = hb4;
            #pragma unroll
            for (int kt = 0; kt < 4; ++kt) {
                short8 h8 = *reinterpret_cast<const short8*>(ap + kt * 32 + q * 8);
                acc = MFMA(Whd[kt], h8, acc);
            }
            if (d0 < DIN) {
                float* op = out + ((size_t)(b0 + a * 16 + c) * T_FUT + s_) * DIN + d0;
                op[0] = acc[0];
                if (q == 0) { op[1] = acc[1]; op[2] = acc[2]; op[3] = acc[3]; }
            }
        }
    }
#undef GRU_STEP
}

extern "C" void kernel_launch(void* const* d_in, const int* in_sizes, int n_in,
                              void* d_out, int out_size, void* d_ws, size_t ws_size,
                              hipStream_t stream)
{
    (void)in_sizes; (void)n_in; (void)d_ws; (void)ws_size; (void)out_size;
    gru_tracemodel_kernel<<<dim3(B_TOT / BT), dim3(512), 0, stream>>>(
        (const float*)d_in[0],  (const float*)d_in[1],
        (const float*)d_in[2],  (const float*)d_in[3],
        (const float*)d_in[4],  (const float*)d_in[5],
        (const float*)d_in[6],  (const float*)d_in[7],
        (const float*)d_in[8],  (const float*)d_in[9],
        (const float*)d_in[10], (const float*)d_in[11],
        (float*)d_out);
}